// Round 8
// baseline (158.605 us; speedup 1.0000x reference)
//
#include <hip/hip_runtime.h>
#include <cstddef>

constexpr int NN  = 40000;   // nodes
constexpr int NE  = 640000;  // edges
constexpr int DIM = 128;     // D_IN == D_OUT
constexpr int CAP = 48;      // per-node neighbor capacity (max deg ~36 for Poisson(16))
constexpr int PLANE = NN * 64;  // shorts per 64-dim plane

typedef __attribute__((ext_vector_type(8))) short short8;   // 8 bf16 (4 VGPRs)
typedef __attribute__((ext_vector_type(4))) float floatx4;  // MFMA acc

// fp32 -> bf16 with round-to-nearest-even
__device__ __forceinline__ unsigned short f2bf(float x) {
    union { float f; unsigned int i; } v; v.f = x;
    unsigned int u = v.i;
    return (unsigned short)((u + 0x7fffu + ((u >> 16) & 1u)) >> 16);
}
__device__ __forceinline__ float bflo2f(unsigned int u) {   // low bf16 -> f32
    union { unsigned int i; float f; } v; v.i = u << 16; return v.f;
}
__device__ __forceinline__ float bfhi2f(unsigned int u) {   // high bf16 -> f32
    union { unsigned int i; float f; } v; v.i = u & 0xffff0000u; return v.f;
}

// ---------------------------------------------------------------------------
// Fused prep: [blocks 0..2499] cast feat fp32 -> bf16 planes featb[2][NN][64]
//             [blocks 2500..2627] transpose+cast W to Wc[4][128][64]
//             [blocks 2628..2784] zero cnt[NN]
// ---------------------------------------------------------------------------
__global__ __launch_bounds__(256) void k_prep(
    const float* __restrict__ feat, const float* __restrict__ Wself,
    const float* __restrict__ Wneigh, unsigned short* __restrict__ featb,
    unsigned short* __restrict__ Wc, int* __restrict__ cnt)
{
    int b = blockIdx.x, t = threadIdx.x;
    if (b < 2500) {
        int idx8 = b * 256 + t;          // 640000 groups of 8 elements
        int n  = idx8 >> 4;              // 16 groups per row
        int d0 = (idx8 & 15) << 3;       // dim base 0,8,...,120
        const float4* fp =
            reinterpret_cast<const float4*>(feat + (size_t)n * DIM + d0);
        float4 v0 = fp[0], v1 = fp[1];
        unsigned int p0 = (unsigned int)f2bf(v0.x) | ((unsigned int)f2bf(v0.y) << 16);
        unsigned int p1 = (unsigned int)f2bf(v0.z) | ((unsigned int)f2bf(v0.w) << 16);
        unsigned int p2 = (unsigned int)f2bf(v1.x) | ((unsigned int)f2bf(v1.y) << 16);
        unsigned int p3 = (unsigned int)f2bf(v1.z) | ((unsigned int)f2bf(v1.w) << 16);
        int plane = d0 >> 6, off = d0 & 63;
        *reinterpret_cast<uint4*>(
            featb + (size_t)plane * PLANE + (size_t)n * 64 + off) =
            make_uint4(p0, p1, p2, p3);
    } else if (b < 2628) {
        int idx = (b - 2500) * 256 + t;  // 0..32767
        int c = idx >> 13, n = (idx >> 6) & 127, kp = idx & 63;
        int k = c * 64 + kp;
        float w = (k < DIM) ? Wself[(size_t)k * DIM + n]
                            : Wneigh[(size_t)(k - DIM) * DIM + n];
        Wc[idx] = f2bf(w);
    } else {
        int i = (b - 2628) * 256 + t;
        if (i < NN) cnt[i] = 0;
    }
}

// ---------------------------------------------------------------------------
// Build fixed-capacity adjacency with uint16 source ids.
// ---------------------------------------------------------------------------
__global__ __launch_bounds__(256) void k_fill(
    const int* __restrict__ src, const int* __restrict__ dst,
    int* __restrict__ cnt, unsigned short* __restrict__ colf)
{
    int e = blockIdx.x * blockDim.x + threadIdx.x;
    if (e < NE) {
        int d = dst[e];
        int pos = atomicAdd(&cnt[d], 1);
        if (pos < CAP) colf[d * CAP + pos] = (unsigned short)src[e];
    }
}

// ---------------------------------------------------------------------------
// Plane-partitioned gather + mean. Each block handles ONE 64-dim plane
// (plane = blockIdx&1 -> round-robin XCD dispatch gives each XCD L2 a 5.1 MB
// working set instead of 10.2 MB). One node per wave: lanes 0..31 even edges,
// lanes 32..63 odd edges; cross-half reduce via __shfl_xor(,32).
// ALL __shfl sites execute with every lane active (wave-uniform loop bounds;
// remainder clamps the source lane and predicates only the load) — shfl from
// exec-inactive lanes is undefined on CDNA (R7 bug).
// ---------------------------------------------------------------------------
__global__ __launch_bounds__(256) void k_gather(
    const unsigned int* __restrict__ fb32,   // featb viewed as [2][NN][32] uint
    const int* __restrict__ cnt,
    const unsigned short* __restrict__ colf,
    unsigned int* __restrict__ hnb32)        // hnb viewed as [2][NN][32] uint
{
    int plane = blockIdx.x & 1;
    int w = threadIdx.x >> 6;
    int n = (blockIdx.x >> 1) * 4 + w;
    int lane = threadIdx.x & 63;
    int half = lane >> 5;      // 0: even edges, 1: odd edges
    int off = lane & 31;       // uint offset within the plane row

    int deg = cnt[n];
    int m = min(deg, CAP);
    int sv = (lane < m) ? (int)colf[n * CAP + lane] : 0;

    const unsigned int* base = fb32 + (size_t)plane * (NN * 32) + off;

    float a0 = 0.f, b0 = 0.f, a1 = 0.f, b1 = 0.f;
    int j = 0;
    // Main loop: wave-uniform bound m>>1 -> both halves fully active, and
    // every source edge index 2(j+q)+half <= 2*((m>>1)-1)+1 <= m-1 is valid.
    for (; j + 3 < (m >> 1); j += 4) {
        int e0 = 2 * j + half;
        int s0 = __shfl(sv, e0),     s1 = __shfl(sv, e0 + 2);
        int s2 = __shfl(sv, e0 + 4), s3 = __shfl(sv, e0 + 6);
        unsigned int u0 = base[s0 * 32];
        unsigned int u1 = base[s1 * 32];
        unsigned int u2 = base[s2 * 32];
        unsigned int u3 = base[s3 * 32];
        a0 += bflo2f(u0); b0 += bfhi2f(u0);
        a1 += bflo2f(u1); b1 += bfhi2f(u1);
        a0 += bflo2f(u2); b0 += bfhi2f(u2);
        a1 += bflo2f(u3); b1 += bfhi2f(u3);
    }
    // Remainder: wave-uniform bound ceil(m/2); shfl unconditional with
    // clamped source lane, load/accumulate predicated per lane.
    int mh_max = (m + 1) >> 1;
    for (; j < mh_max; ++j) {
        int e = 2 * j + half;
        int s = __shfl(sv, (e < m) ? e : 0);
        if (e < m) {
            unsigned int u = base[s * 32];
            a0 += bflo2f(u); b0 += bfhi2f(u);
        }
    }
    float ax = a0 + a1, by = b0 + b1;
    ax += __shfl_xor(ax, 32);
    by += __shfl_xor(by, 32);

    if (half == 0) {
        float inv = 1.0f / fmaxf((float)deg, 1.0f);
        hnb32[(size_t)plane * (NN * 32) + (size_t)n * 32 + off] =
            (unsigned int)f2bf(ax * inv) | ((unsigned int)f2bf(by * inv) << 16);
    }
}

// ---------------------------------------------------------------------------
// Fused GEMM (R5-proven): out = [featb | hnb] (K=256 bf16) @ Wc + biases.
// 250 blocks x 160 rows; 5 waves; 16x16x32 bf16 MFMA; all staging via
// global_load_lds width=16 (sources are contiguous bf16 planes).
// ---------------------------------------------------------------------------
__global__ __launch_bounds__(320) void k_gemm(
    const unsigned short* __restrict__ featb,  // [2][NN][64]
    const unsigned short* __restrict__ hnb,    // [2][NN][64]
    const unsigned short* __restrict__ Wc,     // [4][128][64]
    const float* __restrict__ bself, const float* __restrict__ bneigh,
    float* __restrict__ out)                   // [NN,128] fp32
{
    __shared__ unsigned short As[160 * 64];  // 20480 B
    __shared__ unsigned short Bs[128 * 64];  // 16384 B

    int t = threadIdx.x;
    int w = t >> 6;
    int lane = t & 63;
    int base_m = blockIdx.x * 160;

    floatx4 acc[2][8];
    #pragma unroll
    for (int a = 0; a < 2; ++a)
        #pragma unroll
        for (int b = 0; b < 8; ++b) acc[a][b] = (floatx4)0.f;

    for (int c = 0; c < 4; ++c) {
        // ---- stage A chunk (20480 B): plane c of featb (c<2) or hnb ----
        const unsigned short* srcp =
            ((c < 2) ? featb + (size_t)c * PLANE
                     : hnb + (size_t)(c - 2) * PLANE) + (size_t)base_m * 64;
        #pragma unroll
        for (int it = 0; it < 4; ++it) {          // 1280 slots / 320 threads
            int slot = t + it * 320;
            __builtin_amdgcn_global_load_lds(
                (const __attribute__((address_space(1))) unsigned int*)(srcp + slot * 8),
                (__attribute__((address_space(3))) unsigned int*)(As + slot * 8),
                16, 0, 0);
        }
        // ---- stage B chunk (16384 B): threads 0..255 ----
        if (t < 256) {
            const unsigned short* bp = Wc + (size_t)c * 128 * 64;
            #pragma unroll
            for (int it = 0; it < 4; ++it) {      // 1024 slots / 256 threads
                int slot = t + it * 256;
                __builtin_amdgcn_global_load_lds(
                    (const __attribute__((address_space(1))) unsigned int*)(bp + slot * 8),
                    (__attribute__((address_space(3))) unsigned int*)(Bs + slot * 8),
                    16, 0, 0);
            }
        }
        __syncthreads();

        // ---- 2 k-steps of 32 ----
        #pragma unroll
        for (int s = 0; s < 2; ++s) {
            int koff = s * 32 + (lane >> 4) * 8;
            short8 af[2];
            #pragma unroll
            for (int mt = 0; mt < 2; ++mt) {
                int m = w * 32 + mt * 16 + (lane & 15);
                af[mt] = *reinterpret_cast<const short8*>(As + m * 64 + koff);
            }
            #pragma unroll
            for (int nt = 0; nt < 8; ++nt) {
                int n = nt * 16 + (lane & 15);
                short8 bf = *reinterpret_cast<const short8*>(Bs + n * 64 + koff);
                acc[0][nt] = __builtin_amdgcn_mfma_f32_16x16x32_bf16(
                    af[0], bf, acc[0][nt], 0, 0, 0);
                acc[1][nt] = __builtin_amdgcn_mfma_f32_16x16x32_bf16(
                    af[1], bf, acc[1][nt], 0, 0, 0);
            }
        }
        __syncthreads();
    }

    // ---- epilogue: C/D layout col=lane&15, row=(lane>>4)*4+reg ----
    int colb = lane & 15;
    int quad = lane >> 4;
    #pragma unroll
    for (int nt = 0; nt < 8; ++nt) {
        int col = nt * 16 + colb;
        float bb = bself[col] + bneigh[col];
        #pragma unroll
        for (int mt = 0; mt < 2; ++mt) {
            #pragma unroll
            for (int r = 0; r < 4; ++r) {
                int row = base_m + w * 32 + mt * 16 + quad * 4 + r;
                out[(size_t)row * DIM + col] = acc[mt][nt][r] + bb;
            }
        }
    }
}

// ---------------------------------------------------------------------------
extern "C" void kernel_launch(void* const* d_in, const int* in_sizes, int n_in,
                              void* d_out, int out_size, void* d_ws, size_t ws_size,
                              hipStream_t stream)
{
    const float* feat   = (const float*)d_in[0];
    const int*   src    = (const int*)d_in[1];
    const int*   dst    = (const int*)d_in[2];
    const float* Wself  = (const float*)d_in[3];
    const float* bself  = (const float*)d_in[4];
    const float* Wneigh = (const float*)d_in[5];
    const float* bneigh = (const float*)d_in[6];
    float* out = (float*)d_out;

    // Workspace layout (bytes):
    //   featb [2][NN][64] bf16 @ 0           (10,240,000)
    //   hnb   [2][NN][64] bf16 @ 10,240,000  (10,240,000)
    //   colf  [NN][CAP]   u16  @ 20,480,000  ( 3,840,000)
    //   Wc    [4][128][64]bf16 @ 24,320,000  (    65,536)
    //   cnt   [NN]        i32  @ 24,385,536  (   160,000)
    char* ws = (char*)d_ws;
    unsigned short* featb = (unsigned short*)(ws);
    unsigned short* hnb   = (unsigned short*)(ws + 10240000);
    unsigned short* colf  = (unsigned short*)(ws + 20480000);
    unsigned short* Wc    = (unsigned short*)(ws + 24320000);
    int*            cnt   = (int*)(ws + 24385536);

    k_prep<<<2785, 256, 0, stream>>>(feat, Wself, Wneigh, featb, Wc, cnt);

    k_fill<<<(NE + 255) / 256, 256, 0, stream>>>(src, dst, cnt, colf);

    // Plane-partitioned gather: 2 planes x (NN/4) node groups.
    k_gather<<<(NN / 4) * 2, 256, 0, stream>>>(
        (const unsigned int*)featb, cnt, colf, (unsigned int*)hnb);

    k_gemm<<<NN / 160, 320, 0, stream>>>(featb, hnb, Wc, bself, bneigh, out);
}

// Round 9
// 150.526 us; speedup vs baseline: 1.0537x; 1.0537x over previous
//
#include <hip/hip_runtime.h>
#include <cstddef>

constexpr int NN  = 40000;   // nodes
constexpr int NE  = 640000;  // edges
constexpr int DIM = 128;     // D_IN == D_OUT
constexpr int CAP = 48;      // per-node neighbor capacity (max deg ~36 for Poisson(16))
constexpr int PLANE = NN * 64;  // shorts per 64-dim plane

typedef __attribute__((ext_vector_type(8))) short short8;   // 8 bf16 (4 VGPRs)
typedef __attribute__((ext_vector_type(4))) float floatx4;  // MFMA acc

// fp32 -> bf16 with round-to-nearest-even
__device__ __forceinline__ unsigned short f2bf(float x) {
    union { float f; unsigned int i; } v; v.f = x;
    unsigned int u = v.i;
    return (unsigned short)((u + 0x7fffu + ((u >> 16) & 1u)) >> 16);
}
__device__ __forceinline__ float bflo2f(unsigned int u) {   // low bf16 -> f32
    union { unsigned int i; float f; } v; v.i = u << 16; return v.f;
}
__device__ __forceinline__ float bfhi2f(unsigned int u) {   // high bf16 -> f32
    union { unsigned int i; float f; } v; v.i = u & 0xffff0000u; return v.f;
}

// ---------------------------------------------------------------------------
// Fused prep: [blocks 0..2499] cast feat fp32 -> bf16 planes featb[2][NN][64]
//             [blocks 2500..2627] transpose+cast W to Wc[4][128][64]
//             [blocks 2628..2784] zero cnt[NN]
// ---------------------------------------------------------------------------
__global__ __launch_bounds__(256) void k_prep(
    const float* __restrict__ feat, const float* __restrict__ Wself,
    const float* __restrict__ Wneigh, unsigned short* __restrict__ featb,
    unsigned short* __restrict__ Wc, int* __restrict__ cnt)
{
    int b = blockIdx.x, t = threadIdx.x;
    if (b < 2500) {
        int idx8 = b * 256 + t;          // 640000 groups of 8 elements
        int n  = idx8 >> 4;              // 16 groups per row
        int d0 = (idx8 & 15) << 3;       // dim base 0,8,...,120
        const float4* fp =
            reinterpret_cast<const float4*>(feat + (size_t)n * DIM + d0);
        float4 v0 = fp[0], v1 = fp[1];
        unsigned int p0 = (unsigned int)f2bf(v0.x) | ((unsigned int)f2bf(v0.y) << 16);
        unsigned int p1 = (unsigned int)f2bf(v0.z) | ((unsigned int)f2bf(v0.w) << 16);
        unsigned int p2 = (unsigned int)f2bf(v1.x) | ((unsigned int)f2bf(v1.y) << 16);
        unsigned int p3 = (unsigned int)f2bf(v1.z) | ((unsigned int)f2bf(v1.w) << 16);
        int plane = d0 >> 6, off = d0 & 63;
        *reinterpret_cast<uint4*>(
            featb + (size_t)plane * PLANE + (size_t)n * 64 + off) =
            make_uint4(p0, p1, p2, p3);
    } else if (b < 2628) {
        int idx = (b - 2500) * 256 + t;  // 0..32767
        int c = idx >> 13, n = (idx >> 6) & 127, kp = idx & 63;
        int k = c * 64 + kp;
        float w = (k < DIM) ? Wself[(size_t)k * DIM + n]
                            : Wneigh[(size_t)(k - DIM) * DIM + n];
        Wc[idx] = f2bf(w);
    } else {
        int i = (b - 2628) * 256 + t;
        if (i < NN) cnt[i] = 0;
    }
}

// ---------------------------------------------------------------------------
// Build fixed-capacity adjacency with uint16 source ids.
// ---------------------------------------------------------------------------
__global__ __launch_bounds__(256) void k_fill(
    const int* __restrict__ src, const int* __restrict__ dst,
    int* __restrict__ cnt, unsigned short* __restrict__ colf)
{
    int e = blockIdx.x * blockDim.x + threadIdx.x;
    if (e < NE) {
        int d = dst[e];
        int pos = atomicAdd(&cnt[d], 1);
        if (pos < CAP) colf[d * CAP + pos] = (unsigned short)src[e];
    }
}

// ---------------------------------------------------------------------------
// Gather + mean over bf16 planes (R5-proven): one wave per node, lane covers
// 2 dims (one uint = 2 bf16 per row). Neighbor indices prefetched into lanes,
// broadcast via shfl; 8-deep load unroll for latency ILP. All shfl sites run
// with every lane active (no divergent control flow around them).
// ---------------------------------------------------------------------------
__global__ __launch_bounds__(256) void k_gather(
    const unsigned int* __restrict__ fb32,   // featb viewed as [2][NN][32] uint
    const int* __restrict__ cnt,
    const unsigned short* __restrict__ colf,
    unsigned int* __restrict__ hnb32)        // hnb viewed as [2][NN][32] uint
{
    int gtid = blockIdx.x * blockDim.x + threadIdx.x;
    int n = gtid >> 6;
    if (n >= NN) return;
    int lane = threadIdx.x & 63;

    int deg = cnt[n];
    int m = min(deg, CAP);
    int sv = (lane < m) ? (int)colf[n * CAP + lane] : 0;

    int vb = (lane >> 5) * (NN * 32) + (lane & 31);   // plane base + lane offset
    float a0 = 0.f, b0 = 0.f, a1 = 0.f, b1 = 0.f;
    int i = 0;
    for (; i + 7 < m; i += 8) {
        unsigned int u[8];
        #pragma unroll
        for (int q = 0; q < 8; ++q) {
            int s = __shfl(sv, i + q);
            u[q] = fb32[vb + s * 32];
        }
        #pragma unroll
        for (int q = 0; q < 8; q += 2) {
            a0 += bflo2f(u[q]);     b0 += bfhi2f(u[q]);
            a1 += bflo2f(u[q + 1]); b1 += bfhi2f(u[q + 1]);
        }
    }
    for (; i < m; ++i) {
        int s = __shfl(sv, i);
        unsigned int u0 = fb32[vb + s * 32];
        a0 += bflo2f(u0); b0 += bfhi2f(u0);
    }
    float inv = 1.0f / fmaxf((float)deg, 1.0f);
    float ax = (a0 + a1) * inv, ay = (b0 + b1) * inv;
    hnb32[vb + n * 32] = (unsigned int)f2bf(ax) | ((unsigned int)f2bf(ay) << 16);
}

// ---------------------------------------------------------------------------
// Fused GEMM (R5-proven): out = [featb | hnb] (K=256 bf16) @ Wc + biases.
// 250 blocks x 160 rows; 5 waves; 16x16x32 bf16 MFMA; all staging via
// global_load_lds width=16 (sources are contiguous bf16 planes).
// Epilogue uses nontemporal stores (out is write-once, never re-read).
// ---------------------------------------------------------------------------
__global__ __launch_bounds__(320) void k_gemm(
    const unsigned short* __restrict__ featb,  // [2][NN][64]
    const unsigned short* __restrict__ hnb,    // [2][NN][64]
    const unsigned short* __restrict__ Wc,     // [4][128][64]
    const float* __restrict__ bself, const float* __restrict__ bneigh,
    float* __restrict__ out)                   // [NN,128] fp32
{
    __shared__ unsigned short As[160 * 64];  // 20480 B
    __shared__ unsigned short Bs[128 * 64];  // 16384 B

    int t = threadIdx.x;
    int w = t >> 6;
    int lane = t & 63;
    int base_m = blockIdx.x * 160;

    floatx4 acc[2][8];
    #pragma unroll
    for (int a = 0; a < 2; ++a)
        #pragma unroll
        for (int b = 0; b < 8; ++b) acc[a][b] = (floatx4)0.f;

    for (int c = 0; c < 4; ++c) {
        // ---- stage A chunk (20480 B): plane c of featb (c<2) or hnb ----
        const unsigned short* srcp =
            ((c < 2) ? featb + (size_t)c * PLANE
                     : hnb + (size_t)(c - 2) * PLANE) + (size_t)base_m * 64;
        #pragma unroll
        for (int it = 0; it < 4; ++it) {          // 1280 slots / 320 threads
            int slot = t + it * 320;
            __builtin_amdgcn_global_load_lds(
                (const __attribute__((address_space(1))) unsigned int*)(srcp + slot * 8),
                (__attribute__((address_space(3))) unsigned int*)(As + slot * 8),
                16, 0, 0);
        }
        // ---- stage B chunk (16384 B): threads 0..255 ----
        if (t < 256) {
            const unsigned short* bp = Wc + (size_t)c * 128 * 64;
            #pragma unroll
            for (int it = 0; it < 4; ++it) {      // 1024 slots / 256 threads
                int slot = t + it * 256;
                __builtin_amdgcn_global_load_lds(
                    (const __attribute__((address_space(1))) unsigned int*)(bp + slot * 8),
                    (__attribute__((address_space(3))) unsigned int*)(Bs + slot * 8),
                    16, 0, 0);
            }
        }
        __syncthreads();

        // ---- 2 k-steps of 32 ----
        #pragma unroll
        for (int s = 0; s < 2; ++s) {
            int koff = s * 32 + (lane >> 4) * 8;
            short8 af[2];
            #pragma unroll
            for (int mt = 0; mt < 2; ++mt) {
                int m = w * 32 + mt * 16 + (lane & 15);
                af[mt] = *reinterpret_cast<const short8*>(As + m * 64 + koff);
            }
            #pragma unroll
            for (int nt = 0; nt < 8; ++nt) {
                int n = nt * 16 + (lane & 15);
                short8 bf = *reinterpret_cast<const short8*>(Bs + n * 64 + koff);
                acc[0][nt] = __builtin_amdgcn_mfma_f32_16x16x32_bf16(
                    af[0], bf, acc[0][nt], 0, 0, 0);
                acc[1][nt] = __builtin_amdgcn_mfma_f32_16x16x32_bf16(
                    af[1], bf, acc[1][nt], 0, 0, 0);
            }
        }
        __syncthreads();
    }

    // ---- epilogue: C/D layout col=lane&15, row=(lane>>4)*4+reg ----
    int colb = lane & 15;
    int quad = lane >> 4;
    #pragma unroll
    for (int nt = 0; nt < 8; ++nt) {
        int col = nt * 16 + colb;
        float bb = bself[col] + bneigh[col];
        #pragma unroll
        for (int mt = 0; mt < 2; ++mt) {
            #pragma unroll
            for (int r = 0; r < 4; ++r) {
                int row = base_m + w * 32 + mt * 16 + quad * 4 + r;
                __builtin_nontemporal_store(acc[mt][nt][r] + bb,
                                            out + (size_t)row * DIM + col);
            }
        }
    }
}

// ---------------------------------------------------------------------------
extern "C" void kernel_launch(void* const* d_in, const int* in_sizes, int n_in,
                              void* d_out, int out_size, void* d_ws, size_t ws_size,
                              hipStream_t stream)
{
    const float* feat   = (const float*)d_in[0];
    const int*   src    = (const int*)d_in[1];
    const int*   dst    = (const int*)d_in[2];
    const float* Wself  = (const float*)d_in[3];
    const float* bself  = (const float*)d_in[4];
    const float* Wneigh = (const float*)d_in[5];
    const float* bneigh = (const float*)d_in[6];
    float* out = (float*)d_out;

    // Workspace layout (bytes):
    //   featb [2][NN][64] bf16 @ 0           (10,240,000)
    //   hnb   [2][NN][64] bf16 @ 10,240,000  (10,240,000)
    //   colf  [NN][CAP]   u16  @ 20,480,000  ( 3,840,000)
    //   Wc    [4][128][64]bf16 @ 24,320,000  (    65,536)
    //   cnt   [NN]        i32  @ 24,385,536  (   160,000)
    char* ws = (char*)d_ws;
    unsigned short* featb = (unsigned short*)(ws);
    unsigned short* hnb   = (unsigned short*)(ws + 10240000);
    unsigned short* colf  = (unsigned short*)(ws + 20480000);
    unsigned short* Wc    = (unsigned short*)(ws + 24320000);
    int*            cnt   = (int*)(ws + 24385536);

    k_prep<<<2785, 256, 0, stream>>>(feat, Wself, Wneigh, featb, Wc, cnt);

    k_fill<<<(NE + 255) / 256, 256, 0, stream>>>(src, dst, cnt, colf);

    k_gather<<<(NN * 64) / 256, 256, 0, stream>>>(
        (const unsigned int*)featb, cnt, colf, (unsigned int*)hnb);

    k_gemm<<<NN / 160, 320, 0, stream>>>(featb, hnb, Wc, bself, bneigh, out);
}